// Round 1
// baseline (155.330 us; speedup 1.0000x reference)
//
#include <hip/hip_runtime.h>
#include <hip/hip_bf16.h>
#include <stdint.h>

// ---------------------------------------------------------------------------
// NF4 dequant + linear:  out[M,N] = x[M,K] @ W[N,K]^T + bias,  W = NF4 dequant
// M=1024, N=11008, K=4096.  Strategy: dequant W->bf16 (ws), x->bf16 (ws),
// then m97-style 128x128 bf16 MFMA GEMM (B^T layout) with global_load_lds
// width-16 and XOR-swizzled LDS (pre-swizzled global source, rule #21).
// ---------------------------------------------------------------------------

using short8 = __attribute__((ext_vector_type(8))) short;
using f32x4  = __attribute__((ext_vector_type(4))) float;

#define AS1 __attribute__((address_space(1)))
#define AS3 __attribute__((address_space(3)))

__device__ __forceinline__ void gload16(const void* g, void* l) {
  __builtin_amdgcn_global_load_lds((const AS1 uint32_t*)g, (AS3 uint32_t*)l, 16, 0, 0);
}

__constant__ float NF4_CONST[16] = {
  -1.0f, -0.6961928009986877f, -0.5250730514526367f, -0.39491748809814453f,
  -0.28444138169288635f, -0.18477343022823334f, -0.09105003625154495f, 0.0f,
  0.07958029955625534f, 0.16093020141124725f, 0.24611230194568634f,
  0.33791524171829224f, 0.44070982933044434f, 0.5626170039176941f,
  0.7229568362236023f, 1.0f};

__device__ __forceinline__ ushort f2bf(float f) {
  union { float f; uint32_t u; } v; v.f = f;
  uint32_t r = (v.u + 0x7FFFu + ((v.u >> 16) & 1u)) >> 16;
  return (ushort)r;
}

// ---- Pass 1: dequantize w_idx(int32) * absmax -> bf16 weights -------------
__global__ __launch_bounds__(256) void dequant_nf4(
    const int* __restrict__ widx, const float* __restrict__ absmax,
    ushort* __restrict__ W) {
  __shared__ float lut[16];
  if (threadIdx.x < 16) lut[threadIdx.x] = NF4_CONST[threadIdx.x];
  __syncthreads();
  const long long t = (long long)blockIdx.x * 256 + threadIdx.x;
  const long long base = t * 8;   // 8 weights per thread, all in one 64-block
  const int4 i0 = *(const int4*)(widx + base);
  const int4 i1 = *(const int4*)(widx + base + 4);
  const float s = absmax[base >> 6];
  uint4 o;
  o.x = (uint32_t)f2bf(lut[i0.x] * s) | ((uint32_t)f2bf(lut[i0.y] * s) << 16);
  o.y = (uint32_t)f2bf(lut[i0.z] * s) | ((uint32_t)f2bf(lut[i0.w] * s) << 16);
  o.z = (uint32_t)f2bf(lut[i1.x] * s) | ((uint32_t)f2bf(lut[i1.y] * s) << 16);
  o.w = (uint32_t)f2bf(lut[i1.z] * s) | ((uint32_t)f2bf(lut[i1.w] * s) << 16);
  *(uint4*)(W + base) = o;
}

// ---- Pass 2: x f32 -> bf16 ------------------------------------------------
__global__ __launch_bounds__(256) void f32_to_bf16(
    const float* __restrict__ in, ushort* __restrict__ out) {
  const int t = blockIdx.x * 256 + threadIdx.x;
  const int base = t * 8;
  const float4 a = *(const float4*)(in + base);
  const float4 b = *(const float4*)(in + base + 4);
  uint4 o;
  o.x = (uint32_t)f2bf(a.x) | ((uint32_t)f2bf(a.y) << 16);
  o.y = (uint32_t)f2bf(a.z) | ((uint32_t)f2bf(a.w) << 16);
  o.z = (uint32_t)f2bf(b.x) | ((uint32_t)f2bf(b.y) << 16);
  o.w = (uint32_t)f2bf(b.z) | ((uint32_t)f2bf(b.w) << 16);
  *(uint4*)(out + base) = o;
}

// ---- Pass 3: bf16 GEMM, C[M,N] = A[M,K] * B[N,K]^T + bias -----------------
// 128x128 tile, BK=64, 4 waves (2x2), each wave 64x64 via 4x4 frags of
// 16x16x32.  LDS XOR-swizzle: logical slot s (16B) of row r lives at phys
// slot s^(r&7); staged via pre-swizzled global source + linear gload_lds.
#define BM 128
#define BN 128
#define BKK 64

__global__ __launch_bounds__(256, 2) void gemm_bt(
    const ushort* __restrict__ A, const ushort* __restrict__ B,
    const float* __restrict__ bias, float* __restrict__ C,
    const int M, const int N, const int K) {
  __shared__ char lds[(BM * BKK + BN * BKK) * 2];  // 32 KB
  const int tid  = threadIdx.x;
  const int wid  = tid >> 6;
  const int lane = tid & 63;
  const int row0 = blockIdx.y * BM;
  const int col0 = blockIdx.x * BN;
  const int wr = wid >> 1, wc = wid & 1;

  // staging source pointers (pre-swizzled global addresses)
  const ushort* gsrcA[4];
  const ushort* gsrcB[4];
#pragma unroll
  for (int i = 0; i < 4; ++i) {
    const int u = tid + i * 256;            // 16B-unit index within tile
    const int r = u >> 3;                   // tile row
    const int slog = (u & 7) ^ (r & 7);     // logical slot that lands here
    gsrcA[i] = A + (size_t)(row0 + r) * K + slog * 8;
    gsrcB[i] = B + (size_t)(col0 + r) * K + slog * 8;
  }

  // LDS read byte-offsets (loop-invariant)
  int offA[2][4], offB[2][4];
#pragma unroll
  for (int ks = 0; ks < 2; ++ks) {
#pragma unroll
    for (int m = 0; m < 4; ++m) {
      const int ra = wr * 64 + m * 16 + (lane & 15);
      offA[ks][m] = ra * 128 + (((ks * 4 + (lane >> 4)) ^ (ra & 7)) * 16);
      const int rb = wc * 64 + m * 16 + (lane & 15);
      offB[ks][m] = 16384 + rb * 128 + (((ks * 4 + (lane >> 4)) ^ (rb & 7)) * 16);
    }
  }

  f32x4 acc[4][4] = {};

  for (int kt = 0; kt < K; kt += BKK) {
#pragma unroll
    for (int i = 0; i < 4; ++i) {
      gload16(gsrcA[i] + kt, lds + i * 4096 + wid * 1024);
      gload16(gsrcB[i] + kt, lds + 16384 + i * 4096 + wid * 1024);
    }
    __syncthreads();   // compiler drains vmcnt before s_barrier
#pragma unroll
    for (int ks = 0; ks < 2; ++ks) {
      short8 af[4], bv[4];
#pragma unroll
      for (int m = 0; m < 4; ++m) af[m] = *(const short8*)(lds + offA[ks][m]);
#pragma unroll
      for (int n = 0; n < 4; ++n) bv[n] = *(const short8*)(lds + offB[ks][n]);
#pragma unroll
      for (int m = 0; m < 4; ++m)
#pragma unroll
        for (int n = 0; n < 4; ++n)
          acc[m][n] = __builtin_amdgcn_mfma_f32_16x16x32_bf16(
              af[m], bv[n], acc[m][n], 0, 0, 0);
    }
    __syncthreads();
  }

  // epilogue: C/D layout col=lane&15, row=(lane>>4)*4+j  (m89-verified)
#pragma unroll
  for (int n = 0; n < 4; ++n) {
    const int gc = col0 + wc * 64 + n * 16 + (lane & 15);
    const float bvadd = bias[gc];
#pragma unroll
    for (int m = 0; m < 4; ++m) {
      const int gr0 = row0 + wr * 64 + m * 16 + ((lane >> 4) * 4);
#pragma unroll
      for (int j = 0; j < 4; ++j)
        C[(size_t)(gr0 + j) * N + gc] = acc[m][n][j] + bvadd;
    }
  }
}

// ---- Fallback (only if ws_size too small): correct but slow ---------------
__global__ __launch_bounds__(256) void fallback_kernel(
    const float* __restrict__ x, const int* __restrict__ widx,
    const float* __restrict__ absmax, const float* __restrict__ bias,
    float* __restrict__ out, const int M, const int N, const int K) {
  __shared__ float w[4096];
  const int o = blockIdx.x;
  for (int k = threadIdx.x; k < K; k += 256) {
    const long long fi = (long long)o * K + k;
    w[k] = NF4_CONST[widx[fi]] * absmax[fi >> 6];
  }
  __syncthreads();
  for (int m = threadIdx.x; m < M; m += 256) {
    float acc = bias[o];
    const float* xr = x + (size_t)m * K;
    for (int k = 0; k < K; ++k) acc += xr[k] * w[k];
    out[(size_t)m * N + o] = acc;
  }
}

extern "C" void kernel_launch(void* const* d_in, const int* in_sizes, int n_in,
                              void* d_out, int out_size, void* d_ws, size_t ws_size,
                              hipStream_t stream) {
  const float* x      = (const float*)d_in[0];
  const int*   widx   = (const int*)d_in[1];
  const float* absmax = (const float*)d_in[2];
  const float* bias   = (const float*)d_in[3];
  float* out = (float*)d_out;

  const int N = in_sizes[3];                 // 11008
  const int K = in_sizes[1] / N;             // 4096
  const int M = in_sizes[0] / K;             // 1024
  const long long wElems = (long long)N * K; // 45,088,768
  const long long xElems = (long long)M * K; // 4,194,304
  const size_t wsNeed = (size_t)(wElems + xElems) * 2;

  if (ws_size >= wsNeed && (M % BM) == 0 && (N % BN) == 0 && (K % BKK) == 0) {
    ushort* Wbf = (ushort*)d_ws;
    ushort* Xbf = (ushort*)d_ws + wElems;
    dequant_nf4<<<(int)(wElems / (256 * 8)), 256, 0, stream>>>(widx, absmax, Wbf);
    f32_to_bf16<<<(int)(xElems / (256 * 8)), 256, 0, stream>>>(x, Xbf);
    dim3 grid(N / BN, M / BM);
    gemm_bt<<<grid, 256, 0, stream>>>(Xbf, Wbf, bias, out, M, N, K);
  } else {
    fallback_kernel<<<N, 256, 0, stream>>>(x, widx, absmax, bias, out, M, N, K);
  }
}

// Round 2
// 153.188 us; speedup vs baseline: 1.0140x; 1.0140x over previous
//
#include <hip/hip_runtime.h>
#include <hip/hip_bf16.h>
#include <stdint.h>

// ---------------------------------------------------------------------------
// NF4 dequant + linear:  out[M,N] = x[M,K] @ W[N,K]^T + bias
// Pass1: dequant W -> bf16 (HBM-floor bound, 43us).  Pass2: x -> bf16.
// Pass3: 256x256 8-phase bf16 GEMM (T1 XCD-swizzle + T2 LDS XOR-swizzle +
//        T3/T4 counted-vmcnt phase pipeline + T5 setprio).
// ---------------------------------------------------------------------------

using short8 = __attribute__((ext_vector_type(8))) short;
using f32x4  = __attribute__((ext_vector_type(4))) float;

#define AS1 __attribute__((address_space(1)))
#define AS3 __attribute__((address_space(3)))

__device__ __forceinline__ void gload16(const void* g, void* l) {
  __builtin_amdgcn_global_load_lds((const AS1 uint32_t*)g, (AS3 uint32_t*)l, 16, 0, 0);
}

__constant__ float NF4_CONST[16] = {
  -1.0f, -0.6961928009986877f, -0.5250730514526367f, -0.39491748809814453f,
  -0.28444138169288635f, -0.18477343022823334f, -0.09105003625154495f, 0.0f,
  0.07958029955625534f, 0.16093020141124725f, 0.24611230194568634f,
  0.33791524171829224f, 0.44070982933044434f, 0.5626170039176941f,
  0.7229568362236023f, 1.0f};

__device__ __forceinline__ ushort f2bf(float f) {
  union { float f; uint32_t u; } v; v.f = f;
  uint32_t r = (v.u + 0x7FFFu + ((v.u >> 16) & 1u)) >> 16;
  return (ushort)r;
}

// ---- Pass 1: dequantize w_idx(int32) * absmax -> bf16 weights -------------
__global__ __launch_bounds__(256) void dequant_nf4(
    const int* __restrict__ widx, const float* __restrict__ absmax,
    ushort* __restrict__ W) {
  __shared__ float lut[16];
  if (threadIdx.x < 16) lut[threadIdx.x] = NF4_CONST[threadIdx.x];
  __syncthreads();
  const long long t = (long long)blockIdx.x * 256 + threadIdx.x;
  const long long base = t * 8;
  const int4 i0 = *(const int4*)(widx + base);
  const int4 i1 = *(const int4*)(widx + base + 4);
  const float s = absmax[base >> 6];
  uint4 o;
  o.x = (uint32_t)f2bf(lut[i0.x] * s) | ((uint32_t)f2bf(lut[i0.y] * s) << 16);
  o.y = (uint32_t)f2bf(lut[i0.z] * s) | ((uint32_t)f2bf(lut[i0.w] * s) << 16);
  o.z = (uint32_t)f2bf(lut[i1.x] * s) | ((uint32_t)f2bf(lut[i1.y] * s) << 16);
  o.w = (uint32_t)f2bf(lut[i1.z] * s) | ((uint32_t)f2bf(lut[i1.w] * s) << 16);
  *(uint4*)(W + base) = o;
}

// ---- Pass 2: x f32 -> bf16 ------------------------------------------------
__global__ __launch_bounds__(256) void f32_to_bf16(
    const float* __restrict__ in, ushort* __restrict__ out) {
  const int t = blockIdx.x * 256 + threadIdx.x;
  const int base = t * 8;
  const float4 a = *(const float4*)(in + base);
  const float4 b = *(const float4*)(in + base + 4);
  uint4 o;
  o.x = (uint32_t)f2bf(a.x) | ((uint32_t)f2bf(a.y) << 16);
  o.y = (uint32_t)f2bf(a.z) | ((uint32_t)f2bf(a.w) << 16);
  o.z = (uint32_t)f2bf(b.x) | ((uint32_t)f2bf(b.y) << 16);
  o.w = (uint32_t)f2bf(b.z) | ((uint32_t)f2bf(b.w) << 16);
  *(uint4*)(out + base) = o;
}

// ===========================================================================
// Pass 3a: 256x256 8-phase GEMM.  C[M,N] = A[M,K] * B[N,K]^T + bias.
// 512 thr = 8 waves (2M x 4N); per-wave C = 128x64 split as 2x(64) rows and
// 2x(32) cols across the two LDS half-buffers, so each phase reads exactly
// one A-half and one B-half (quadrant), enabling half-granular re-staging.
// LDS 128KB: A [2 dbuf][2 half][128 rows][64 k] bf16, B same at +64KB.
// Swizzle: 16B slot s of row r lives at phys slot s^(r&7)  (conflict-free).
// Schedule per iter (tiles t=2j buf0, t+1 buf1), stage 1 half/phase:
//  ph1 rd A0B0(b0)  st A1(t+1)   ph5 rd A0B0(b1)  st A1(t+2)
//  ph2 rd B1(b0)    st B1(t+1)   ph6 rd B1(b1)    st B1(t+2)
//  ph3 rd A1(b0)    st A0(t+2)   ph7 rd A1(b1)    st A0(t+3)
//  ph4 (regs only)  st B0(t+2)*  ph8 (regs only)  st B0(t+3)*
//  (* = vmcnt(4) before barrier: leaves exactly the 2 youngest half-tiles
//   in flight; every slot freed >=2 phases before its re-stage — derived,
//   race-checked by slot-free/deadline table.)
// ===========================================================================

#define BAR() asm volatile("s_barrier" ::: "memory")
#define VMCNT4() asm volatile("s_waitcnt vmcnt(4)" ::: "memory")

#define STAGE_A(d, h, tk) do {                                            \
  gload16(sA0 + (size_t)(h) * hK + (tk), lds + (d)*32768 + (h)*16384 + d0);\
  gload16(sA1 + (size_t)(h) * hK + (tk), lds + (d)*32768 + (h)*16384 + d1);\
} while (0)
#define STAGE_B(d, h, tk) do {                                            \
  gload16(sB0 + (size_t)(h) * hK + (tk), lds + 65536 + (d)*32768 + (h)*16384 + d0);\
  gload16(sB1 + (size_t)(h) * hK + (tk), lds + 65536 + (d)*32768 + (h)*16384 + d1);\
} while (0)

#define LDA(d, hA) do {                                                   \
  const char* _b = lds + (d)*32768 + (hA)*16384 + aRow;                   \
  _Pragma("unroll") for (int mm = 0; mm < 4; ++mm) {                      \
    af[mm*2+0] = *(const short8*)(_b + mm*2048 + kt0);                    \
    af[mm*2+1] = *(const short8*)(_b + mm*2048 + kt1);                    \
  } } while (0)
#define LDB(BF, d, hB) do {                                               \
  const char* _b = lds + 65536 + (d)*32768 + (hB)*16384 + bRow;           \
  _Pragma("unroll") for (int nn = 0; nn < 2; ++nn) {                      \
    BF[nn*2+0] = *(const short8*)(_b + nn*2048 + kt0);                    \
    BF[nn*2+1] = *(const short8*)(_b + nn*2048 + kt1);                    \
  } } while (0)

#define MMA(hA, hB, BF) do {                                              \
  __builtin_amdgcn_s_setprio(1);                                          \
  _Pragma("unroll") for (int mm = 0; mm < 4; ++mm)                        \
    _Pragma("unroll") for (int nn = 0; nn < 2; ++nn) {                    \
      acc[(hA)*4+mm][(hB)*2+nn] = __builtin_amdgcn_mfma_f32_16x16x32_bf16(\
          af[mm*2+0], BF[nn*2+0], acc[(hA)*4+mm][(hB)*2+nn], 0, 0, 0);    \
      acc[(hA)*4+mm][(hB)*2+nn] = __builtin_amdgcn_mfma_f32_16x16x32_bf16(\
          af[mm*2+1], BF[nn*2+1], acc[(hA)*4+mm][(hB)*2+nn], 0, 0, 0);    \
    }                                                                     \
  __builtin_amdgcn_s_setprio(0); } while (0)

__global__ __launch_bounds__(512, 2) void gemm256(
    const ushort* __restrict__ A, const ushort* __restrict__ B,
    const float* __restrict__ bias, float* __restrict__ C,
    const int M, const int N, const int K) {
  extern __shared__ char lds[];
  const int tid = threadIdx.x;
  const int wid = tid >> 6, lane = tid & 63;
  const int wr = wid >> 2, wc = wid & 3;

  // T1: bijective XCD swizzle (m204) on column-major-flattened id
  const int nwg = gridDim.x;
  int id = blockIdx.x;
  { const int q = nwg >> 3, r = nwg & 7; const int x = id & 7, ix = id >> 3;
    id = (x < r ? x * (q + 1) : r * (q + 1) + (x - r) * q) + ix; }
  const int mb = M >> 8;
  const int by = id % mb, bx = id / mb;
  const int row0 = by * 256, col0 = bx * 256;

  // staging per-thread constants (pre-swizzled global source, rule #21)
  const int u0 = tid, u1 = tid + 512;
  const int r0 = u0 >> 3, l0 = (u0 & 7) ^ (r0 & 7);
  const int r1 = u1 >> 3, l1 = (u1 & 7) ^ (r1 & 7);
  const size_t Ks = (size_t)K, hK = 128 * Ks;
  const ushort* sA0 = A + (size_t)(row0 + r0) * Ks + l0 * 8;
  const ushort* sA1 = A + (size_t)(row0 + r1) * Ks + l1 * 8;
  const ushort* sB0 = B + (size_t)(col0 + r0) * Ks + l0 * 8;
  const ushort* sB1 = B + (size_t)(col0 + r1) * Ks + l1 * 8;
  const int d0 = tid * 16, d1 = tid * 16 + 8192;

  // ds_read constants: row's XOR term reduces to lane&7 (rows are 16-aligned)
  const int aRow = (wr * 64 + (lane & 15)) * 128;
  const int bRow = (wc * 32 + (lane & 15)) * 128;
  const int kt0 = (((lane >> 4) + 0) ^ (lane & 7)) * 16;
  const int kt1 = (((lane >> 4) + 4) ^ (lane & 7)) * 16;

  f32x4 acc[8][4] = {};
  short8 af[8], b0f[4], b1f[4];

  const int NT = K >> 6;          // 64 K-tiles, NT even, >= 4
  // Prologue: tile0 (4 halves) + tile1 A0,B0  = 12 loads
  STAGE_A(0, 0, 0); STAGE_B(0, 0, 0);
  STAGE_A(0, 1, 0); STAGE_B(0, 1, 0);
  STAGE_A(1, 0, 64); STAGE_B(1, 0, 64);
  VMCNT4();                       // tile0's 8 loads landed
  BAR();

  for (int t = 0; t < NT; t += 2) {
    const int k1 = (t + 1) << 6;
    const int k2 = (t + 2 < NT ? t + 2 : NT - 1) << 6;
    const int k3 = (t + 3 < NT ? t + 3 : NT - 1) << 6;
    // ph1
    LDA(0, 0); LDB(b0f, 0, 0);
    STAGE_A(1, 1, k1);
    BAR(); MMA(0, 0, b0f); BAR();
    // ph2
    LDB(b1f, 0, 1);
    STAGE_B(1, 1, k1);
    BAR(); MMA(0, 1, b1f); BAR();
    // ph3
    LDA(0, 1);
    STAGE_A(0, 0, k2);
    BAR(); MMA(1, 0, b0f); BAR();
    // ph4
    STAGE_B(0, 0, k2);
    VMCNT4();
    BAR(); MMA(1, 1, b1f); BAR();
    // ph5
    LDA(1, 0); LDB(b0f, 1, 0);
    STAGE_A(0, 1, k2);
    BAR(); MMA(0, 0, b0f); BAR();
    // ph6
    LDB(b1f, 1, 1);
    STAGE_B(0, 1, k2);
    BAR(); MMA(0, 1, b1f); BAR();
    // ph7
    LDA(1, 1);
    STAGE_A(1, 0, k3);
    BAR(); MMA(1, 0, b0f); BAR();
    // ph8
    STAGE_B(1, 0, k3);
    VMCNT4();
    BAR(); MMA(1, 1, b1f); BAR();
  }

  // epilogue: frag (m,n): rows split m<4 -> half0, cols n<2 -> half0
#pragma unroll
  for (int n = 0; n < 4; ++n) {
    const int gc = col0 + ((n < 2) ? (wc * 32 + n * 16)
                                   : (128 + wc * 32 + (n - 2) * 16)) + (lane & 15);
    const float bb = bias[gc];
#pragma unroll
    for (int m = 0; m < 8; ++m) {
      const int gr = row0 + ((m < 4) ? (wr * 64 + m * 16)
                                     : (128 + wr * 64 + (m - 4) * 16)) + ((lane >> 4) * 4);
#pragma unroll
      for (int j = 0; j < 4; ++j)
        C[(size_t)(gr + j) * N + gc] = acc[m][n][j] + bb;
    }
  }
}

// ---- Pass 3b fallback: verified 128x128 m97-structure GEMM ----------------
#define BM 128
#define BN 128
#define BKK 64

__global__ __launch_bounds__(256, 2) void gemm_bt(
    const ushort* __restrict__ A, const ushort* __restrict__ B,
    const float* __restrict__ bias, float* __restrict__ C,
    const int M, const int N, const int K) {
  __shared__ char lds[(BM * BKK + BN * BKK) * 2];
  const int tid  = threadIdx.x;
  const int wid  = tid >> 6;
  const int lane = tid & 63;
  const int row0 = blockIdx.y * BM;
  const int col0 = blockIdx.x * BN;
  const int wr = wid >> 1, wc = wid & 1;

  const ushort* gsrcA[4];
  const ushort* gsrcB[4];
#pragma unroll
  for (int i = 0; i < 4; ++i) {
    const int u = tid + i * 256;
    const int r = u >> 3;
    const int slog = (u & 7) ^ (r & 7);
    gsrcA[i] = A + (size_t)(row0 + r) * K + slog * 8;
    gsrcB[i] = B + (size_t)(col0 + r) * K + slog * 8;
  }
  int offA[2][4], offB[2][4];
#pragma unroll
  for (int ks = 0; ks < 2; ++ks) {
#pragma unroll
    for (int m = 0; m < 4; ++m) {
      const int ra = wr * 64 + m * 16 + (lane & 15);
      offA[ks][m] = ra * 128 + (((ks * 4 + (lane >> 4)) ^ (ra & 7)) * 16);
      const int rb = wc * 64 + m * 16 + (lane & 15);
      offB[ks][m] = 16384 + rb * 128 + (((ks * 4 + (lane >> 4)) ^ (rb & 7)) * 16);
    }
  }
  f32x4 acc[4][4] = {};
  for (int kt = 0; kt < K; kt += BKK) {
#pragma unroll
    for (int i = 0; i < 4; ++i) {
      gload16(gsrcA[i] + kt, lds + i * 4096 + wid * 1024);
      gload16(gsrcB[i] + kt, lds + 16384 + i * 4096 + wid * 1024);
    }
    __syncthreads();
#pragma unroll
    for (int ks = 0; ks < 2; ++ks) {
      short8 afv[4], bv[4];
#pragma unroll
      for (int m = 0; m < 4; ++m) afv[m] = *(const short8*)(lds + offA[ks][m]);
#pragma unroll
      for (int n = 0; n < 4; ++n) bv[n] = *(const short8*)(lds + offB[ks][n]);
#pragma unroll
      for (int m = 0; m < 4; ++m)
#pragma unroll
        for (int n = 0; n < 4; ++n)
          acc[m][n] = __builtin_amdgcn_mfma_f32_16x16x32_bf16(
              afv[m], bv[n], acc[m][n], 0, 0, 0);
    }
    __syncthreads();
  }
#pragma unroll
  for (int n = 0; n < 4; ++n) {
    const int gc = col0 + wc * 64 + n * 16 + (lane & 15);
    const float bvadd = bias[gc];
#pragma unroll
    for (int m = 0; m < 4; ++m) {
      const int gr0 = row0 + wr * 64 + m * 16 + ((lane >> 4) * 4);
#pragma unroll
      for (int j = 0; j < 4; ++j)
        C[(size_t)(gr0 + j) * N + gc] = acc[m][n][j] + bvadd;
    }
  }
}

// ---- last-resort fallback -------------------------------------------------
__global__ __launch_bounds__(256) void fallback_kernel(
    const float* __restrict__ x, const int* __restrict__ widx,
    const float* __restrict__ absmax, const float* __restrict__ bias,
    float* __restrict__ out, const int M, const int N, const int K) {
  __shared__ float w[4096];
  const int o = blockIdx.x;
  for (int k = threadIdx.x; k < K; k += 256) {
    const long long fi = (long long)o * K + k;
    w[k] = NF4_CONST[widx[fi]] * absmax[fi >> 6];
  }
  __syncthreads();
  for (int m = threadIdx.x; m < M; m += 256) {
    float acc = bias[o];
    const float* xr = x + (size_t)m * K;
    for (int k = 0; k < K; ++k) acc += xr[k] * w[k];
    out[(size_t)m * N + o] = acc;
  }
}

extern "C" void kernel_launch(void* const* d_in, const int* in_sizes, int n_in,
                              void* d_out, int out_size, void* d_ws, size_t ws_size,
                              hipStream_t stream) {
  const float* x      = (const float*)d_in[0];
  const int*   widx   = (const int*)d_in[1];
  const float* absmax = (const float*)d_in[2];
  const float* bias   = (const float*)d_in[3];
  float* out = (float*)d_out;

  const int N = in_sizes[3];
  const int K = in_sizes[1] / N;
  const int M = in_sizes[0] / K;
  const long long wElems = (long long)N * K;
  const long long xElems = (long long)M * K;
  const size_t wsNeed = (size_t)(wElems + xElems) * 2;

  if (ws_size >= wsNeed && (K % 128) == 0) {
    ushort* Wbf = (ushort*)d_ws;
    ushort* Xbf = (ushort*)d_ws + wElems;
    dequant_nf4<<<(int)(wElems / (256 * 8)), 256, 0, stream>>>(widx, absmax, Wbf);
    f32_to_bf16<<<(int)(xElems / (256 * 8)), 256, 0, stream>>>(x, Xbf);
    if ((M % 256) == 0 && (N % 256) == 0 && (K >> 6) >= 4 && ((K >> 6) & 1) == 0) {
      static int attr_set = 0;
      if (!attr_set) {
        hipFuncSetAttribute((const void*)gemm256,
                            hipFuncAttributeMaxDynamicSharedMemorySize, 131072);
        attr_set = 1;
      }
      const int nblk = (N / 256) * (M / 256);
      gemm256<<<dim3(nblk), dim3(512), 131072, stream>>>(Xbf, Wbf, bias, out, M, N, K);
    } else if ((M % BM) == 0 && (N % BN) == 0) {
      dim3 grid(N / BN, M / BM);
      gemm_bt<<<grid, 256, 0, stream>>>(Xbf, Wbf, bias, out, M, N, K);
    } else {
      fallback_kernel<<<N, 256, 0, stream>>>(x, widx, absmax, bias, out, M, N, K);
    }
  } else {
    fallback_kernel<<<N, 256, 0, stream>>>(x, widx, absmax, bias, out, M, N, K);
  }
}